// Round 7
// baseline (213.206 us; speedup 1.0000x reference)
//
#include <hip/hip_runtime.h>
#include <math.h>

// Problem constants
#define B_N   4
#define CIN   21
#define HIDC  48
#define H0    81
#define NP    6561      // 81*81
#define HH    324
#define NPH   104976    // 324*324

__device__ __forceinline__ float tanh_fast(float x) {
    float e = __expf(2.f * x);
    return 1.f - 2.f / (e + 1.f);
}

// ---------------------------------------------------------------------------
// K1 v6 (unchanged): conv1 both heads (21 -> 96 = 48 o + 48 g), relu.
// ---------------------------------------------------------------------------
__global__ __launch_bounds__(256) void k1_conv1(
    const float* __restrict__ x,
    const float* __restrict__ w1o, const float* __restrict__ b1o,
    const float* __restrict__ w1g, const float* __restrict__ b1g,
    float* __restrict__ hid_o, float* __restrict__ hid_g)
{
    __shared__ __align__(16) float wt[189 * 12];  // [ict*12 + oc]
    __shared__ float bs[12];
    const int tid = threadIdx.x;
    const int grp = blockIdx.y;          // 0..7 ; 0..3 -> head_o, 4..7 -> head_g
    const int b   = blockIdx.z;
    const bool head_o = (grp < 4);
    const int ocb = (grp & 3) * 12;      // oc base within the head
    const float* wsrc = head_o ? w1o : w1g;
    for (int i = tid; i < 189 * 12; i += 256) {
        const int ict = i / 12, oc = i - ict * 12;
        wt[i] = wsrc[(ocb + oc) * 189 + ict];
    }
    if (tid < 12) bs[tid] = (head_o ? b1o : b1g)[ocb + tid];
    __syncthreads();

    const int px = blockIdx.x * 256 + tid;
    const bool valid = (px < NP);
    const int oy = px / H0, ox = px - oy * H0;
    const float* xb = x + (size_t)b * CIN * NP;

    float acc[12];
    #pragma unroll
    for (int j = 0; j < 12; j++) acc[j] = bs[j];

    for (int ic = 0; ic < CIN; ic++) {
        const float* xc = xb + ic * NP;
        float xv[9];
        #pragma unroll
        for (int ky = 0; ky < 3; ky++) {
            const int iy = oy + ky - 1;
            const bool rok = valid && ((unsigned)iy < (unsigned)H0);
            #pragma unroll
            for (int kx = 0; kx < 3; kx++) {
                const int ix = ox + kx - 1;
                const bool ok = rok && ((unsigned)ix < (unsigned)H0);
                xv[ky * 3 + kx] = ok ? xc[iy * H0 + ix] : 0.f;
            }
        }
        #pragma unroll
        for (int tap = 0; tap < 9; tap++) {
            const float4 w0 = *(const float4*)&wt[(ic * 9 + tap) * 12];
            const float4 w1 = *(const float4*)&wt[(ic * 9 + tap) * 12 + 4];
            const float4 w2 = *(const float4*)&wt[(ic * 9 + tap) * 12 + 8];
            const float wj[12] = {w0.x, w0.y, w0.z, w0.w, w1.x, w1.y, w1.z, w1.w,
                                  w2.x, w2.y, w2.z, w2.w};
            const float xvt = xv[tap];
            #pragma unroll
            for (int j = 0; j < 12; j++) acc[j] = fmaf(xvt, wj[j], acc[j]);
        }
    }

    if (valid) {
        float* outp = (head_o ? hid_o : hid_g) + ((size_t)b * HIDC + ocb) * NP + px;
        #pragma unroll
        for (int j = 0; j < 12; j++) outp[j * NP] = fmaxf(acc[j], 0.f);
    }
}

// ---------------------------------------------------------------------------
// K2UP v5: identical to v3 (round-5 best, 143.8 us) except conv2's ky loop
// is FULLY UNROLLED: all 108 hid gathers (o+g) hoist into one issue burst
// per thread instead of 3 rounds of 36 separated by s_waitcnt stalls.
// v4/v6 established conv2 is in-flight-bytes limited (latency x parallelism),
// not served-from-where limited; tripling outstanding loads per wave at the
// cost of ~1 wave/SIMD of occupancy nets ~2.25x latency coverage.
// ---------------------------------------------------------------------------
__global__ __launch_bounds__(256) void k2up(
    const float* __restrict__ x,
    const float* __restrict__ hid_o, const float* __restrict__ hid_g,
    const float* __restrict__ w2o, const float* __restrict__ b2o,
    const float* __restrict__ w2g, const float* __restrict__ b2g,
    const float* __restrict__ beta,
    float* __restrict__ v_out, float* __restrict__ y_out,
    float* __restrict__ gup_out)
{
    __shared__ __align__(16) float wo_s[HIDC * 9 * 8];  // 13824 B
    __shared__ float wg_s[HIDC * 9];                    // 1728 B
    __shared__ float red[4][32][12];                    // 6144 B
    __shared__ float res_s[32][29];                     // 3712 B, stride 29 coprime w/ 32
    __shared__ float xs[CIN][4][H0];                    // 27216 B: 4 reflected rows
    const int tid = threadIdx.x;
    const int b = blockIdx.y;

    const int pl  = tid & 31;
    const int s   = tid >> 5;                // 0..7
    const int w   = tid >> 6;                // wave
    const int px0 = blockIdx.x * 32;
    const int px  = px0 + pl;
    const bool valid = (px < NP);
    const int py  = px / H0, pxc = px - py * H0;
    const int pr0 = px0 / H0;                // first row touched by this block

    // ---- stage x rows: slot t = reflect(pr0-1+t), fully coalesced -------
    {
        const float* xb = x + (size_t)b * CIN * NP;
        for (int i = tid; i < CIN * 4 * H0; i += 256) {
            const int c = i / (4 * H0), rem = i - c * (4 * H0);
            const int t = rem / H0, col = rem - t * H0;
            int r = pr0 - 1 + t;
            r = (r < 0) ? -r : r;
            r = (r > H0 - 1) ? 2 * (H0 - 1) - r : r;
            (&xs[0][0][0])[i] = xb[c * NP + r * H0 + col];
        }
    }

    // ---- stage conv2 weights --------------------------------------------
    for (int i = tid; i < HIDC * 9 * 8; i += 256) {
        const int d = i / (HIDC * 9), r = i - d * (HIDC * 9);
        wo_s[r * 8 + d] = w2o[i];
    }
    for (int i = tid; i < HIDC * 9; i += 256) wg_s[i] = w2g[i];
    __syncthreads();

    // ---- conv2 partials: FULLY UNROLLED (the one change vs v3) ----------
    const int ic0 = s * 6;
    const float* po = hid_o + ((size_t)b * HIDC + ic0) * NP;
    const float* pg = hid_g + ((size_t)b * HIDC + ic0) * NP;

    float a[8] = {0.f, 0.f, 0.f, 0.f, 0.f, 0.f, 0.f, 0.f};
    float ag = 0.f;

    #pragma unroll
    for (int ky = 0; ky < 3; ky++) {
        const int iy = py + ky - 1;
        const bool rok = valid && ((unsigned)iy < (unsigned)H0);
        #pragma unroll
        for (int kx = 0; kx < 3; kx++) {
            const int ix = pxc + kx - 1;
            const bool ok = rok && ((unsigned)ix < (unsigned)H0);
            const int off = iy * H0 + ix;
            const int tap = ky * 3 + kx;
            #pragma unroll
            for (int j = 0; j < 6; j++) {
                const float vo = ok ? po[j * NP + off] : 0.f;
                const float vg = ok ? pg[j * NP + off] : 0.f;
                const int wb = ((ic0 + j) * 9 + tap) * 8;
                const float4 wA = *(const float4*)&wo_s[wb];
                const float4 wB = *(const float4*)&wo_s[wb + 4];
                a[0] = fmaf(vo, wA.x, a[0]); a[1] = fmaf(vo, wA.y, a[1]);
                a[2] = fmaf(vo, wA.z, a[2]); a[3] = fmaf(vo, wA.w, a[3]);
                a[4] = fmaf(vo, wB.x, a[4]); a[5] = fmaf(vo, wB.y, a[5]);
                a[6] = fmaf(vo, wB.z, a[6]); a[7] = fmaf(vo, wB.w, a[7]);
                ag = fmaf(vg, wg_s[(ic0 + j) * 9 + tap], ag);
            }
        }
    }

    #pragma unroll
    for (int n = 0; n < 8; n++) a[n] += __shfl_xor(a[n], 32);
    ag += __shfl_xor(ag, 32);
    if ((tid & 32) == 0) {
        #pragma unroll
        for (int n = 0; n < 8; n++) red[w][pl][n] = a[n];
        red[w][pl][8] = ag;
    }
    __syncthreads();

    // ---- mask epilogue (32 threads) -------------------------------------
    if (tid < 32 && valid) {
        float v[8];
        #pragma unroll
        for (int n = 0; n < 8; n++)
            v[n] = tanh_fast(red[0][tid][n] + red[1][tid][n] + red[2][tid][n]
                             + red[3][tid][n] + b2o[n]);
        const float agf = red[0][tid][8] + red[1][tid][8] + red[2][tid][8]
                        + red[3][tid][8] + b2g[0];
        const float g = 1.f / (1.f + __expf(-agf));

        constexpr float DT[8][9] = {
            {-1, 0, 1, -1, 0, 1, -1, 0, 1},
            {-1,-1, 0, -1, 0, 1,  0, 1, 1},
            {-1,-1,-1,  0, 0, 0,  1, 1, 1},
            { 0,-1,-1,  1, 0,-1,  1, 1, 0},
            { 1, 0,-1,  1, 0,-1,  1, 0,-1},
            { 1, 1, 0,  1, 0,-1,  0,-1,-1},
            { 1, 1, 1,  0, 0, 0, -1,-1,-1},
            { 0, 1, 1, -1, 0, 1, -1,-1, 0}};
        float ker[9];
        #pragma unroll
        for (int n = 0; n < 9; n++) {
            float t = 0.f;
            #pragma unroll
            for (int d = 0; d < 8; d++) t += v[d] * DT[d][n];
            ker[n] = -0.125f * t;
        }
        ker[4] += 2.5f;
        float mx = ker[0];
        #pragma unroll
        for (int n = 1; n < 9; n++) mx = fmaxf(mx, ker[n]);
        float exn[9], sum = 0.f;
        #pragma unroll
        for (int n = 0; n < 9; n++) { exn[n] = __expf((ker[n] - mx) * 2.0f); sum += exn[n]; }
        const float rs = 1.f / sum;
        float mean = 0.f;
        #pragma unroll
        for (int n = 0; n < 9; n++) mean += ker[n];
        mean *= (1.f / 9.f);
        float den = 1e-8f;
        #pragma unroll
        for (int n = 0; n < 9; n++) den += fabsf(ker[n] - mean);
        const float rd = 1.f / den;

        #pragma unroll
        for (int n = 0; n < 8; n++) res_s[tid][n] = v[n];
        res_s[tid][8] = g;
        #pragma unroll
        for (int n = 0; n < 9; n++) {
            res_s[tid][9 + n]  = exn[n] * rs;
            res_s[tid][18 + n] = (ker[n] - mean) * rd;
        }
    }
    __syncthreads();

    // ---- v scatter (one iteration: 8 planes x 32 px) --------------------
    if (valid) v_out[((size_t)b * 8 + s) * NP + px] = res_s[pl][s];

    // ---- emit: 22 planes x 32 px items, all data from LDS ---------------
    const float tb = tanh_fast(beta[0]);
    for (int i = tid; i < 22 * 32; i += 256) {
        const int plane = i >> 5, pp = i & 31;
        const int p = px0 + pp;
        if (p >= NP) continue;
        const int ppy = p / H0, ppx = p - ppy * H0;
        const float gv = res_s[pp][8];

        if (plane == 21) {
            float* gdst = gup_out + (size_t)b * NPH;
            #pragma unroll
            for (int dh = 0; dh < 4; dh++)
                *reinterpret_cast<float4*>(gdst + (size_t)(ppy * 4 + dh) * HH + ppx * 4) =
                    make_float4(gv, gv, gv, gv);
            continue;
        }

        // 3x3 reflected window from LDS row cache
        const int d0 = ppy - pr0;        // 0 or 1
        const int xm = (ppx == 0) ? 1 : ppx - 1;
        const int xp = (ppx == H0 - 1) ? H0 - 2 : ppx + 1;
        float w9[9];
        #pragma unroll
        for (int t = 0; t < 3; t++) {
            w9[t * 3 + 0] = xs[plane][d0 + t][xm];
            w9[t * 3 + 1] = xs[plane][d0 + t][ppx];
            w9[t * 3 + 2] = xs[plane][d0 + t][xp];
        }

        float alp = 0.f, ahp = 0.f;
        #pragma unroll
        for (int t = 0; t < 9; t++) {
            alp = fmaf(w9[t], res_s[pp][9 + t],  alp);
            ahp = fmaf(w9[t], res_s[pp][18 + t], ahp);
        }

        const float lam = 0.15f * (1.f - gv);
        const float gh  = tb * gv;

        // per-pixel bilinear coefficients
        int sxv[4]; float wxv[4];
        #pragma unroll
        for (int k = 0; k < 4; k++) {
            const int W = ppx * 4 + k;
            const float xsf = (float)W * (80.f / 323.f);
            int x0 = (int)xsf;
            if (x0 > H0 - 2) x0 = H0 - 2;
            wxv[k] = xsf - (float)x0;
            sxv[k] = x0 - ppx + 1;       // 0 or 1
        }

        float* ydst = y_out + ((size_t)b * CIN + plane) * NPH;
        #pragma unroll
        for (int dh = 0; dh < 4; dh++) {
            const int H = ppy * 4 + dh;
            const float ysf = (float)H * (80.f / 323.f);
            int y0 = (int)ysf;
            if (y0 > H0 - 2) y0 = H0 - 2;
            const float wy = ysf - (float)y0;
            const int sy = y0 - ppy + 1;  // 0 or 1
            const float A0 = sy ? w9[3] : w9[0];
            const float A1 = sy ? w9[4] : w9[1];
            const float A2 = sy ? w9[5] : w9[2];
            const float B0 = sy ? w9[6] : w9[3];
            const float B1 = sy ? w9[7] : w9[4];
            const float B2 = sy ? w9[8] : w9[5];
            float rr[4];
            #pragma unroll
            for (int k = 0; k < 4; k++) {
                const float wx = wxv[k];
                const float top = sxv[k] ? fmaf(A2 - A1, wx, A1) : fmaf(A1 - A0, wx, A0);
                const float bot = sxv[k] ? fmaf(B2 - B1, wx, B1) : fmaf(B1 - B0, wx, B0);
                const float xup = fmaf(bot - top, wy, top);
                rr[k] = fmaf(lam, alp - xup, xup) + gh * ahp;
            }
            *reinterpret_cast<float4*>(ydst + (size_t)H * HH + ppx * 4) =
                make_float4(rr[0], rr[1], rr[2], rr[3]);
        }
    }
}

// ---------------------------------------------------------------------------
extern "C" void kernel_launch(void* const* d_in, const int* in_sizes, int n_in,
                              void* d_out, int out_size, void* d_ws, size_t ws_size,
                              hipStream_t stream)
{
    const float* x    = (const float*)d_in[0];
    const float* w1o  = (const float*)d_in[1];
    const float* b1o  = (const float*)d_in[2];
    const float* w2o  = (const float*)d_in[3];
    const float* b2o  = (const float*)d_in[4];
    const float* w1g  = (const float*)d_in[5];
    const float* b1g  = (const float*)d_in[6];
    const float* w2g  = (const float*)d_in[7];
    const float* b2g  = (const float*)d_in[8];
    const float* beta = (const float*)d_in[9];
    float* out = (float*)d_out;
    float* wsf = (float*)d_ws;

    float* hid_o = wsf;
    float* hid_g = hid_o + (size_t)B_N * HIDC * NP;

    // output layout: y [4,21,324,324], v [4,8,81,81], g_up [4,1,324,324]
    float* y_out = out;
    float* v_out = out + (size_t)B_N * CIN * NPH;
    float* gup   = v_out + (size_t)B_N * 8 * NP;

    k1_conv1<<<dim3((NP + 255) / 256, 8, B_N), 256, 0, stream>>>(
        x, w1o, b1o, w1g, b1g, hid_o, hid_g);
    k2up<<<dim3((NP + 31) / 32, B_N), 256, 0, stream>>>(
        x, hid_o, hid_g, w2o, b2o, w2g, b2g, beta, v_out, y_out, gup);
}

// Round 8
// 152.010 us; speedup vs baseline: 1.4026x; 1.4026x over previous
//
#include <hip/hip_runtime.h>
#include <math.h>

// Problem constants
#define B_N   4
#define CIN   21
#define HIDC  48
#define H0    81
#define NP    6561      // 81*81
#define HH    324
#define NPH   104976    // 324*324
#define HP    83        // padded hid row stride (1-cell zero border)
#define NPP   6889      // 83*83 padded plane size

__device__ __forceinline__ float tanh_fast(float x) {
    float e = __expf(2.f * x);
    return 1.f - 2.f / (e + 1.f);
}

// ---------------------------------------------------------------------------
// K1 v7: conv1 both heads (21 -> 96), relu. Same MLP-first structure as v6,
// but writes hid planes in PADDED 83x83 layout with a zero border, so k2up's
// conv2 loads need no boundary guards (branch-free hot loop). Block 0 of
// each (grp,b) zeroes the 328 border cells of its 12 planes (~15 st/thread).
// ---------------------------------------------------------------------------
__global__ __launch_bounds__(256) void k1_conv1(
    const float* __restrict__ x,
    const float* __restrict__ w1o, const float* __restrict__ b1o,
    const float* __restrict__ w1g, const float* __restrict__ b1g,
    float* __restrict__ hid_o, float* __restrict__ hid_g)
{
    __shared__ __align__(16) float wt[189 * 12];  // [ict*12 + oc]
    __shared__ float bs[12];
    const int tid = threadIdx.x;
    const int grp = blockIdx.y;          // 0..7 ; 0..3 -> head_o, 4..7 -> head_g
    const int b   = blockIdx.z;
    const bool head_o = (grp < 4);
    const int ocb = (grp & 3) * 12;      // oc base within the head
    const float* wsrc = head_o ? w1o : w1g;
    for (int i = tid; i < 189 * 12; i += 256) {
        const int ict = i / 12, oc = i - ict * 12;
        wt[i] = wsrc[(ocb + oc) * 189 + ict];
    }
    if (tid < 12) bs[tid] = (head_o ? b1o : b1g)[ocb + tid];

    float* outp = (head_o ? hid_o : hid_g) + ((size_t)b * HIDC + ocb) * NPP;

    // zero the 328 border cells of this block-group's 12 planes
    if (blockIdx.x == 0) {
        for (int i = tid; i < 12 * 328; i += 256) {
            const int j = i / 328, t = i - j * 328;
            int r, c;
            if (t < 83)       { r = 0;  c = t; }
            else if (t < 166) { r = 82; c = t - 83; }
            else if (t < 247) { r = t - 166 + 1; c = 0; }
            else              { r = t - 247 + 1; c = 82; }
            outp[j * NPP + r * HP + c] = 0.f;
        }
    }
    __syncthreads();

    const int px = blockIdx.x * 256 + tid;
    const bool valid = (px < NP);
    const int oy = px / H0, ox = px - oy * H0;
    const float* xb = x + (size_t)b * CIN * NP;

    float acc[12];
    #pragma unroll
    for (int j = 0; j < 12; j++) acc[j] = bs[j];

    for (int ic = 0; ic < CIN; ic++) {
        const float* xc = xb + ic * NP;
        float xv[9];
        #pragma unroll
        for (int ky = 0; ky < 3; ky++) {
            const int iy = oy + ky - 1;
            const bool rok = valid && ((unsigned)iy < (unsigned)H0);
            #pragma unroll
            for (int kx = 0; kx < 3; kx++) {
                const int ix = ox + kx - 1;
                const bool ok = rok && ((unsigned)ix < (unsigned)H0);
                xv[ky * 3 + kx] = ok ? xc[iy * H0 + ix] : 0.f;
            }
        }
        #pragma unroll
        for (int tap = 0; tap < 9; tap++) {
            const float4 w0 = *(const float4*)&wt[(ic * 9 + tap) * 12];
            const float4 w1 = *(const float4*)&wt[(ic * 9 + tap) * 12 + 4];
            const float4 w2 = *(const float4*)&wt[(ic * 9 + tap) * 12 + 8];
            const float wj[12] = {w0.x, w0.y, w0.z, w0.w, w1.x, w1.y, w1.z, w1.w,
                                  w2.x, w2.y, w2.z, w2.w};
            const float xvt = xv[tap];
            #pragma unroll
            for (int j = 0; j < 12; j++) acc[j] = fmaf(xvt, wj[j], acc[j]);
        }
    }

    if (valid) {
        const int po = oy * HP + ox + HP + 1;   // padded offset (+1 row, +1 col)
        #pragma unroll
        for (int j = 0; j < 12; j++) outp[j * NPP + po] = fmaxf(acc[j], 0.f);
    }
}

// ---------------------------------------------------------------------------
// K2UP v6: identical to v3 (round-5 best, k2up ~44 us) except the conv2
// inner loop is BRANCH-FREE: hid is stored padded (83x83, zero border), so
// all 108 gathers are unconditional loads -- no exec-mask save/restore per
// kx-group, no boundary predicates/cndmasks, free compiler load batching.
// ---------------------------------------------------------------------------
__global__ __launch_bounds__(256) void k2up(
    const float* __restrict__ x,
    const float* __restrict__ hid_o, const float* __restrict__ hid_g,
    const float* __restrict__ w2o, const float* __restrict__ b2o,
    const float* __restrict__ w2g, const float* __restrict__ b2g,
    const float* __restrict__ beta,
    float* __restrict__ v_out, float* __restrict__ y_out,
    float* __restrict__ gup_out)
{
    __shared__ __align__(16) float wo_s[HIDC * 9 * 8];  // 13824 B
    __shared__ float wg_s[HIDC * 9];                    // 1728 B
    __shared__ float red[4][32][12];                    // 6144 B
    __shared__ float res_s[32][29];                     // 3712 B, stride 29 coprime w/ 32
    __shared__ float xs[CIN][4][H0];                    // 27216 B: 4 reflected rows
    const int tid = threadIdx.x;
    const int b = blockIdx.y;

    const int pl  = tid & 31;
    const int s   = tid >> 5;                // 0..7
    const int w   = tid >> 6;                // wave
    const int px0 = blockIdx.x * 32;
    const int px  = px0 + pl;
    const bool valid = (px < NP);
    const int pxq = valid ? px : 0;          // clamp for load addressing only
    const int py  = pxq / H0, pxc = pxq - py * H0;
    const int pr0 = px0 / H0;                // first row touched by this block

    // ---- stage x rows: slot t = reflect(pr0-1+t), fully coalesced -------
    {
        const float* xb = x + (size_t)b * CIN * NP;
        for (int i = tid; i < CIN * 4 * H0; i += 256) {
            const int c = i / (4 * H0), rem = i - c * (4 * H0);
            const int t = rem / H0, col = rem - t * H0;
            int r = pr0 - 1 + t;
            r = (r < 0) ? -r : r;
            r = (r > H0 - 1) ? 2 * (H0 - 1) - r : r;
            (&xs[0][0][0])[i] = xb[c * NP + r * H0 + col];
        }
    }

    // ---- stage conv2 weights --------------------------------------------
    for (int i = tid; i < HIDC * 9 * 8; i += 256) {
        const int d = i / (HIDC * 9), r = i - d * (HIDC * 9);
        wo_s[r * 8 + d] = w2o[i];
    }
    for (int i = tid; i < HIDC * 9; i += 256) wg_s[i] = w2g[i];
    __syncthreads();

    // ---- conv2 partials: BRANCH-FREE (padded hid layout) ----------------
    const int ic0 = s * 6;
    const float* po = hid_o + ((size_t)b * HIDC + ic0) * NPP;
    const float* pg = hid_g + ((size_t)b * HIDC + ic0) * NPP;
    const int base = py * HP + pxc;          // padded addr of (py-1, pxc-1)

    float a[8] = {0.f, 0.f, 0.f, 0.f, 0.f, 0.f, 0.f, 0.f};
    float ag = 0.f;

    #pragma unroll 1
    for (int ky = 0; ky < 3; ky++) {
        #pragma unroll
        for (int kx = 0; kx < 3; kx++) {
            const int off = base + ky * HP + kx;
            const int tap = ky * 3 + kx;
            #pragma unroll
            for (int j = 0; j < 6; j++) {
                const float vo = po[j * NPP + off];
                const float vg = pg[j * NPP + off];
                const int wb = ((ic0 + j) * 9 + tap) * 8;
                const float4 wA = *(const float4*)&wo_s[wb];
                const float4 wB = *(const float4*)&wo_s[wb + 4];
                a[0] = fmaf(vo, wA.x, a[0]); a[1] = fmaf(vo, wA.y, a[1]);
                a[2] = fmaf(vo, wA.z, a[2]); a[3] = fmaf(vo, wA.w, a[3]);
                a[4] = fmaf(vo, wB.x, a[4]); a[5] = fmaf(vo, wB.y, a[5]);
                a[6] = fmaf(vo, wB.z, a[6]); a[7] = fmaf(vo, wB.w, a[7]);
                ag = fmaf(vg, wg_s[(ic0 + j) * 9 + tap], ag);
            }
        }
    }

    #pragma unroll
    for (int n = 0; n < 8; n++) a[n] += __shfl_xor(a[n], 32);
    ag += __shfl_xor(ag, 32);
    if ((tid & 32) == 0) {
        #pragma unroll
        for (int n = 0; n < 8; n++) red[w][pl][n] = a[n];
        red[w][pl][8] = ag;
    }
    __syncthreads();

    // ---- mask epilogue (32 threads) -------------------------------------
    if (tid < 32 && valid) {
        float v[8];
        #pragma unroll
        for (int n = 0; n < 8; n++)
            v[n] = tanh_fast(red[0][tid][n] + red[1][tid][n] + red[2][tid][n]
                             + red[3][tid][n] + b2o[n]);
        const float agf = red[0][tid][8] + red[1][tid][8] + red[2][tid][8]
                        + red[3][tid][8] + b2g[0];
        const float g = 1.f / (1.f + __expf(-agf));

        constexpr float DT[8][9] = {
            {-1, 0, 1, -1, 0, 1, -1, 0, 1},
            {-1,-1, 0, -1, 0, 1,  0, 1, 1},
            {-1,-1,-1,  0, 0, 0,  1, 1, 1},
            { 0,-1,-1,  1, 0,-1,  1, 1, 0},
            { 1, 0,-1,  1, 0,-1,  1, 0,-1},
            { 1, 1, 0,  1, 0,-1,  0,-1,-1},
            { 1, 1, 1,  0, 0, 0, -1,-1,-1},
            { 0, 1, 1, -1, 0, 1, -1,-1, 0}};
        float ker[9];
        #pragma unroll
        for (int n = 0; n < 9; n++) {
            float t = 0.f;
            #pragma unroll
            for (int d = 0; d < 8; d++) t += v[d] * DT[d][n];
            ker[n] = -0.125f * t;
        }
        ker[4] += 2.5f;
        float mx = ker[0];
        #pragma unroll
        for (int n = 1; n < 9; n++) mx = fmaxf(mx, ker[n]);
        float exn[9], sum = 0.f;
        #pragma unroll
        for (int n = 0; n < 9; n++) { exn[n] = __expf((ker[n] - mx) * 2.0f); sum += exn[n]; }
        const float rs = 1.f / sum;
        float mean = 0.f;
        #pragma unroll
        for (int n = 0; n < 9; n++) mean += ker[n];
        mean *= (1.f / 9.f);
        float den = 1e-8f;
        #pragma unroll
        for (int n = 0; n < 9; n++) den += fabsf(ker[n] - mean);
        const float rd = 1.f / den;

        #pragma unroll
        for (int n = 0; n < 8; n++) res_s[tid][n] = v[n];
        res_s[tid][8] = g;
        #pragma unroll
        for (int n = 0; n < 9; n++) {
            res_s[tid][9 + n]  = exn[n] * rs;
            res_s[tid][18 + n] = (ker[n] - mean) * rd;
        }
    }
    __syncthreads();

    // ---- v scatter (one iteration: 8 planes x 32 px) --------------------
    if (valid) v_out[((size_t)b * 8 + s) * NP + px] = res_s[pl][s];

    // ---- emit: 22 planes x 32 px items, all data from LDS ---------------
    const float tb = tanh_fast(beta[0]);
    for (int i = tid; i < 22 * 32; i += 256) {
        const int plane = i >> 5, pp = i & 31;
        const int p = px0 + pp;
        if (p >= NP) continue;
        const int ppy = p / H0, ppx = p - ppy * H0;
        const float gv = res_s[pp][8];

        if (plane == 21) {
            float* gdst = gup_out + (size_t)b * NPH;
            #pragma unroll
            for (int dh = 0; dh < 4; dh++)
                *reinterpret_cast<float4*>(gdst + (size_t)(ppy * 4 + dh) * HH + ppx * 4) =
                    make_float4(gv, gv, gv, gv);
            continue;
        }

        // 3x3 reflected window from LDS row cache
        const int d0 = ppy - pr0;        // 0 or 1
        const int xm = (ppx == 0) ? 1 : ppx - 1;
        const int xp = (ppx == H0 - 1) ? H0 - 2 : ppx + 1;
        float w9[9];
        #pragma unroll
        for (int t = 0; t < 3; t++) {
            w9[t * 3 + 0] = xs[plane][d0 + t][xm];
            w9[t * 3 + 1] = xs[plane][d0 + t][ppx];
            w9[t * 3 + 2] = xs[plane][d0 + t][xp];
        }

        float alp = 0.f, ahp = 0.f;
        #pragma unroll
        for (int t = 0; t < 9; t++) {
            alp = fmaf(w9[t], res_s[pp][9 + t],  alp);
            ahp = fmaf(w9[t], res_s[pp][18 + t], ahp);
        }

        const float lam = 0.15f * (1.f - gv);
        const float gh  = tb * gv;

        // per-pixel bilinear coefficients
        int sxv[4]; float wxv[4];
        #pragma unroll
        for (int k = 0; k < 4; k++) {
            const int W = ppx * 4 + k;
            const float xsf = (float)W * (80.f / 323.f);
            int x0 = (int)xsf;
            if (x0 > H0 - 2) x0 = H0 - 2;
            wxv[k] = xsf - (float)x0;
            sxv[k] = x0 - ppx + 1;       // 0 or 1
        }

        float* ydst = y_out + ((size_t)b * CIN + plane) * NPH;
        #pragma unroll
        for (int dh = 0; dh < 4; dh++) {
            const int H = ppy * 4 + dh;
            const float ysf = (float)H * (80.f / 323.f);
            int y0 = (int)ysf;
            if (y0 > H0 - 2) y0 = H0 - 2;
            const float wy = ysf - (float)y0;
            const int sy = y0 - ppy + 1;  // 0 or 1
            const float A0 = sy ? w9[3] : w9[0];
            const float A1 = sy ? w9[4] : w9[1];
            const float A2 = sy ? w9[5] : w9[2];
            const float B0 = sy ? w9[6] : w9[3];
            const float B1 = sy ? w9[7] : w9[4];
            const float B2 = sy ? w9[8] : w9[5];
            float rr[4];
            #pragma unroll
            for (int k = 0; k < 4; k++) {
                const float wx = wxv[k];
                const float top = sxv[k] ? fmaf(A2 - A1, wx, A1) : fmaf(A1 - A0, wx, A0);
                const float bot = sxv[k] ? fmaf(B2 - B1, wx, B1) : fmaf(B1 - B0, wx, B0);
                const float xup = fmaf(bot - top, wy, top);
                rr[k] = fmaf(lam, alp - xup, xup) + gh * ahp;
            }
            *reinterpret_cast<float4*>(ydst + (size_t)H * HH + ppx * 4) =
                make_float4(rr[0], rr[1], rr[2], rr[3]);
        }
    }
}

// ---------------------------------------------------------------------------
extern "C" void kernel_launch(void* const* d_in, const int* in_sizes, int n_in,
                              void* d_out, int out_size, void* d_ws, size_t ws_size,
                              hipStream_t stream)
{
    const float* x    = (const float*)d_in[0];
    const float* w1o  = (const float*)d_in[1];
    const float* b1o  = (const float*)d_in[2];
    const float* w2o  = (const float*)d_in[3];
    const float* b2o  = (const float*)d_in[4];
    const float* w1g  = (const float*)d_in[5];
    const float* b1g  = (const float*)d_in[6];
    const float* w2g  = (const float*)d_in[7];
    const float* b2g  = (const float*)d_in[8];
    const float* beta = (const float*)d_in[9];
    float* out = (float*)d_out;
    float* wsf = (float*)d_ws;

    float* hid_o = wsf;                                  // [4][48][83*83] padded
    float* hid_g = hid_o + (size_t)B_N * HIDC * NPP;

    // output layout: y [4,21,324,324], v [4,8,81,81], g_up [4,1,324,324]
    float* y_out = out;
    float* v_out = out + (size_t)B_N * CIN * NPH;
    float* gup   = v_out + (size_t)B_N * 8 * NP;

    k1_conv1<<<dim3((NP + 255) / 256, 8, B_N), 256, 0, stream>>>(
        x, w1o, b1o, w1g, b1g, hid_o, hid_g);
    k2up<<<dim3((NP + 31) / 32, B_N), 256, 0, stream>>>(
        x, hid_o, hid_g, w2o, b2o, w2g, b2g, beta, v_out, y_out, gup);
}

// Round 9
// 151.847 us; speedup vs baseline: 1.4041x; 1.0011x over previous
//
#include <hip/hip_runtime.h>
#include <math.h>

// Problem constants
#define B_N   4
#define CIN   21
#define HIDC  48
#define H0    81
#define NP    6561      // 81*81
#define HH    324
#define NPH   104976    // 324*324

__device__ __forceinline__ float tanh_fast(float x) {
    float e = __expf(2.f * x);
    return 1.f - 2.f / (e + 1.f);
}

// ---------------------------------------------------------------------------
// K1 v8: conv1 both heads (21 -> 96), relu. Same MLP-first structure as v6,
// but hid is stored CHANNEL-PAIR-INTERLEAVED: [b][24][NP][2] (float2 elems).
// ocb is 12-aligned -> each block writes 6 aligned pairs (float2 stores,
// half the store instructions, 8B/lane).
// ---------------------------------------------------------------------------
__global__ __launch_bounds__(256) void k1_conv1(
    const float* __restrict__ x,
    const float* __restrict__ w1o, const float* __restrict__ b1o,
    const float* __restrict__ w1g, const float* __restrict__ b1g,
    float* __restrict__ hid_o, float* __restrict__ hid_g)
{
    __shared__ __align__(16) float wt[189 * 12];  // [ict*12 + oc]
    __shared__ float bs[12];
    const int tid = threadIdx.x;
    const int grp = blockIdx.y;          // 0..7 ; 0..3 -> head_o, 4..7 -> head_g
    const int b   = blockIdx.z;
    const bool head_o = (grp < 4);
    const int ocb = (grp & 3) * 12;      // oc base within the head (12-aligned)
    const float* wsrc = head_o ? w1o : w1g;
    for (int i = tid; i < 189 * 12; i += 256) {
        const int ict = i / 12, oc = i - ict * 12;
        wt[i] = wsrc[(ocb + oc) * 189 + ict];
    }
    if (tid < 12) bs[tid] = (head_o ? b1o : b1g)[ocb + tid];
    __syncthreads();

    const int px = blockIdx.x * 256 + tid;
    const bool valid = (px < NP);
    const int oy = px / H0, ox = px - oy * H0;
    const float* xb = x + (size_t)b * CIN * NP;

    float acc[12];
    #pragma unroll
    for (int j = 0; j < 12; j++) acc[j] = bs[j];

    for (int ic = 0; ic < CIN; ic++) {
        const float* xc = xb + ic * NP;
        float xv[9];
        #pragma unroll
        for (int ky = 0; ky < 3; ky++) {
            const int iy = oy + ky - 1;
            const bool rok = valid && ((unsigned)iy < (unsigned)H0);
            #pragma unroll
            for (int kx = 0; kx < 3; kx++) {
                const int ix = ox + kx - 1;
                const bool ok = rok && ((unsigned)ix < (unsigned)H0);
                xv[ky * 3 + kx] = ok ? xc[iy * H0 + ix] : 0.f;
            }
        }
        #pragma unroll
        for (int tap = 0; tap < 9; tap++) {
            const float4 w0 = *(const float4*)&wt[(ic * 9 + tap) * 12];
            const float4 w1 = *(const float4*)&wt[(ic * 9 + tap) * 12 + 4];
            const float4 w2 = *(const float4*)&wt[(ic * 9 + tap) * 12 + 8];
            const float wj[12] = {w0.x, w0.y, w0.z, w0.w, w1.x, w1.y, w1.z, w1.w,
                                  w2.x, w2.y, w2.z, w2.w};
            const float xvt = xv[tap];
            #pragma unroll
            for (int j = 0; j < 12; j++) acc[j] = fmaf(xvt, wj[j], acc[j]);
        }
    }

    if (valid) {
        float* outp = (head_o ? hid_o : hid_g) + ((size_t)b * 24 + (ocb >> 1)) * NP * 2;
        #pragma unroll
        for (int jj = 0; jj < 6; jj++)
            *reinterpret_cast<float2*>(&outp[((size_t)jj * NP + px) * 2]) =
                make_float2(fmaxf(acc[2 * jj], 0.f), fmaxf(acc[2 * jj + 1], 0.f));
    }
}

// ---------------------------------------------------------------------------
// K2UP v7: v3 (round-5 best, 143.8 us total) with ONE change: hid is
// channel-pair-interleaved, so the conv2 gathers are 54 x float2 instead of
// 108 x float -- half the load instructions / latency windows, 8B/lane
// coalescing. ic0 = 6s -> 3 aligned pairs per group, no wave divergence.
// Everything else (grid, LDS layout, guards, epilogue, emit) is v3 verbatim.
// ---------------------------------------------------------------------------
__global__ __launch_bounds__(256) void k2up(
    const float* __restrict__ x,
    const float* __restrict__ hid_o, const float* __restrict__ hid_g,
    const float* __restrict__ w2o, const float* __restrict__ b2o,
    const float* __restrict__ w2g, const float* __restrict__ b2g,
    const float* __restrict__ beta,
    float* __restrict__ v_out, float* __restrict__ y_out,
    float* __restrict__ gup_out)
{
    __shared__ __align__(16) float wo_s[HIDC * 9 * 8];  // 13824 B
    __shared__ float wg_s[HIDC * 9];                    // 1728 B
    __shared__ float red[4][32][12];                    // 6144 B
    __shared__ float res_s[32][29];                     // 3712 B, stride 29 coprime w/ 32
    __shared__ float xs[CIN][4][H0];                    // 27216 B: 4 reflected rows
    const int tid = threadIdx.x;
    const int b = blockIdx.y;

    const int pl  = tid & 31;
    const int s   = tid >> 5;                // 0..7
    const int w   = tid >> 6;                // wave
    const int px0 = blockIdx.x * 32;
    const int px  = px0 + pl;
    const bool valid = (px < NP);
    const int py  = px / H0, pxc = px - py * H0;
    const int pr0 = px0 / H0;                // first row touched by this block

    // ---- stage x rows: slot t = reflect(pr0-1+t), fully coalesced -------
    {
        const float* xb = x + (size_t)b * CIN * NP;
        for (int i = tid; i < CIN * 4 * H0; i += 256) {
            const int c = i / (4 * H0), rem = i - c * (4 * H0);
            const int t = rem / H0, col = rem - t * H0;
            int r = pr0 - 1 + t;
            r = (r < 0) ? -r : r;
            r = (r > H0 - 1) ? 2 * (H0 - 1) - r : r;
            (&xs[0][0][0])[i] = xb[c * NP + r * H0 + col];
        }
    }

    // ---- stage conv2 weights --------------------------------------------
    for (int i = tid; i < HIDC * 9 * 8; i += 256) {
        const int d = i / (HIDC * 9), r = i - d * (HIDC * 9);
        wo_s[r * 8 + d] = w2o[i];
    }
    for (int i = tid; i < HIDC * 9; i += 256) wg_s[i] = w2g[i];
    __syncthreads();

    // ---- conv2 partials: float2 pair loads (the one change vs v3) -------
    const int ic0 = s * 6;
    const float* po = hid_o + ((size_t)b * 24 + 3 * s) * NP * 2;
    const float* pg = hid_g + ((size_t)b * 24 + 3 * s) * NP * 2;

    float a[8] = {0.f, 0.f, 0.f, 0.f, 0.f, 0.f, 0.f, 0.f};
    float ag = 0.f;

    #pragma unroll 1
    for (int ky = 0; ky < 3; ky++) {
        const int iy = py + ky - 1;
        const bool rok = valid && ((unsigned)iy < (unsigned)H0);
        #pragma unroll
        for (int kx = 0; kx < 3; kx++) {
            const int ix = pxc + kx - 1;
            const bool ok = rok && ((unsigned)ix < (unsigned)H0);
            const int off = iy * H0 + ix;
            const int tap = ky * 3 + kx;
            #pragma unroll
            for (int jj = 0; jj < 3; jj++) {
                const float2 vo2 = ok ? *(const float2*)&po[((size_t)jj * NP + off) * 2]
                                      : make_float2(0.f, 0.f);
                const float2 vg2 = ok ? *(const float2*)&pg[((size_t)jj * NP + off) * 2]
                                      : make_float2(0.f, 0.f);
                const int j0 = 2 * jj;
                {
                    const int wb = ((ic0 + j0) * 9 + tap) * 8;
                    const float4 wA = *(const float4*)&wo_s[wb];
                    const float4 wB = *(const float4*)&wo_s[wb + 4];
                    a[0] = fmaf(vo2.x, wA.x, a[0]); a[1] = fmaf(vo2.x, wA.y, a[1]);
                    a[2] = fmaf(vo2.x, wA.z, a[2]); a[3] = fmaf(vo2.x, wA.w, a[3]);
                    a[4] = fmaf(vo2.x, wB.x, a[4]); a[5] = fmaf(vo2.x, wB.y, a[5]);
                    a[6] = fmaf(vo2.x, wB.z, a[6]); a[7] = fmaf(vo2.x, wB.w, a[7]);
                    ag = fmaf(vg2.x, wg_s[(ic0 + j0) * 9 + tap], ag);
                }
                {
                    const int wb = ((ic0 + j0 + 1) * 9 + tap) * 8;
                    const float4 wA = *(const float4*)&wo_s[wb];
                    const float4 wB = *(const float4*)&wo_s[wb + 4];
                    a[0] = fmaf(vo2.y, wA.x, a[0]); a[1] = fmaf(vo2.y, wA.y, a[1]);
                    a[2] = fmaf(vo2.y, wA.z, a[2]); a[3] = fmaf(vo2.y, wA.w, a[3]);
                    a[4] = fmaf(vo2.y, wB.x, a[4]); a[5] = fmaf(vo2.y, wB.y, a[5]);
                    a[6] = fmaf(vo2.y, wB.z, a[6]); a[7] = fmaf(vo2.y, wB.w, a[7]);
                    ag = fmaf(vg2.y, wg_s[(ic0 + j0 + 1) * 9 + tap], ag);
                }
            }
        }
    }

    #pragma unroll
    for (int n = 0; n < 8; n++) a[n] += __shfl_xor(a[n], 32);
    ag += __shfl_xor(ag, 32);
    if ((tid & 32) == 0) {
        #pragma unroll
        for (int n = 0; n < 8; n++) red[w][pl][n] = a[n];
        red[w][pl][8] = ag;
    }
    __syncthreads();

    // ---- mask epilogue (32 threads) -------------------------------------
    if (tid < 32 && valid) {
        float v[8];
        #pragma unroll
        for (int n = 0; n < 8; n++)
            v[n] = tanh_fast(red[0][tid][n] + red[1][tid][n] + red[2][tid][n]
                             + red[3][tid][n] + b2o[n]);
        const float agf = red[0][tid][8] + red[1][tid][8] + red[2][tid][8]
                        + red[3][tid][8] + b2g[0];
        const float g = 1.f / (1.f + __expf(-agf));

        constexpr float DT[8][9] = {
            {-1, 0, 1, -1, 0, 1, -1, 0, 1},
            {-1,-1, 0, -1, 0, 1,  0, 1, 1},
            {-1,-1,-1,  0, 0, 0,  1, 1, 1},
            { 0,-1,-1,  1, 0,-1,  1, 1, 0},
            { 1, 0,-1,  1, 0,-1,  1, 0,-1},
            { 1, 1, 0,  1, 0,-1,  0,-1,-1},
            { 1, 1, 1,  0, 0, 0, -1,-1,-1},
            { 0, 1, 1, -1, 0, 1, -1,-1, 0}};
        float ker[9];
        #pragma unroll
        for (int n = 0; n < 9; n++) {
            float t = 0.f;
            #pragma unroll
            for (int d = 0; d < 8; d++) t += v[d] * DT[d][n];
            ker[n] = -0.125f * t;
        }
        ker[4] += 2.5f;
        float mx = ker[0];
        #pragma unroll
        for (int n = 1; n < 9; n++) mx = fmaxf(mx, ker[n]);
        float exn[9], sum = 0.f;
        #pragma unroll
        for (int n = 0; n < 9; n++) { exn[n] = __expf((ker[n] - mx) * 2.0f); sum += exn[n]; }
        const float rs = 1.f / sum;
        float mean = 0.f;
        #pragma unroll
        for (int n = 0; n < 9; n++) mean += ker[n];
        mean *= (1.f / 9.f);
        float den = 1e-8f;
        #pragma unroll
        for (int n = 0; n < 9; n++) den += fabsf(ker[n] - mean);
        const float rd = 1.f / den;

        #pragma unroll
        for (int n = 0; n < 8; n++) res_s[tid][n] = v[n];
        res_s[tid][8] = g;
        #pragma unroll
        for (int n = 0; n < 9; n++) {
            res_s[tid][9 + n]  = exn[n] * rs;
            res_s[tid][18 + n] = (ker[n] - mean) * rd;
        }
    }
    __syncthreads();

    // ---- v scatter (one iteration: 8 planes x 32 px) --------------------
    if (valid) v_out[((size_t)b * 8 + s) * NP + px] = res_s[pl][s];

    // ---- emit: 22 planes x 32 px items, all data from LDS ---------------
    const float tb = tanh_fast(beta[0]);
    for (int i = tid; i < 22 * 32; i += 256) {
        const int plane = i >> 5, pp = i & 31;
        const int p = px0 + pp;
        if (p >= NP) continue;
        const int ppy = p / H0, ppx = p - ppy * H0;
        const float gv = res_s[pp][8];

        if (plane == 21) {
            float* gdst = gup_out + (size_t)b * NPH;
            #pragma unroll
            for (int dh = 0; dh < 4; dh++)
                *reinterpret_cast<float4*>(gdst + (size_t)(ppy * 4 + dh) * HH + ppx * 4) =
                    make_float4(gv, gv, gv, gv);
            continue;
        }

        // 3x3 reflected window from LDS row cache
        const int d0 = ppy - pr0;        // 0 or 1
        const int xm = (ppx == 0) ? 1 : ppx - 1;
        const int xp = (ppx == H0 - 1) ? H0 - 2 : ppx + 1;
        float w9[9];
        #pragma unroll
        for (int t = 0; t < 3; t++) {
            w9[t * 3 + 0] = xs[plane][d0 + t][xm];
            w9[t * 3 + 1] = xs[plane][d0 + t][ppx];
            w9[t * 3 + 2] = xs[plane][d0 + t][xp];
        }

        float alp = 0.f, ahp = 0.f;
        #pragma unroll
        for (int t = 0; t < 9; t++) {
            alp = fmaf(w9[t], res_s[pp][9 + t],  alp);
            ahp = fmaf(w9[t], res_s[pp][18 + t], ahp);
        }

        const float lam = 0.15f * (1.f - gv);
        const float gh  = tb * gv;

        // per-pixel bilinear coefficients
        int sxv[4]; float wxv[4];
        #pragma unroll
        for (int k = 0; k < 4; k++) {
            const int W = ppx * 4 + k;
            const float xsf = (float)W * (80.f / 323.f);
            int x0 = (int)xsf;
            if (x0 > H0 - 2) x0 = H0 - 2;
            wxv[k] = xsf - (float)x0;
            sxv[k] = x0 - ppx + 1;       // 0 or 1
        }

        float* ydst = y_out + ((size_t)b * CIN + plane) * NPH;
        #pragma unroll
        for (int dh = 0; dh < 4; dh++) {
            const int H = ppy * 4 + dh;
            const float ysf = (float)H * (80.f / 323.f);
            int y0 = (int)ysf;
            if (y0 > H0 - 2) y0 = H0 - 2;
            const float wy = ysf - (float)y0;
            const int sy = y0 - ppy + 1;  // 0 or 1
            const float A0 = sy ? w9[3] : w9[0];
            const float A1 = sy ? w9[4] : w9[1];
            const float A2 = sy ? w9[5] : w9[2];
            const float B0 = sy ? w9[6] : w9[3];
            const float B1 = sy ? w9[7] : w9[4];
            const float B2 = sy ? w9[8] : w9[5];
            float rr[4];
            #pragma unroll
            for (int k = 0; k < 4; k++) {
                const float wx = wxv[k];
                const float top = sxv[k] ? fmaf(A2 - A1, wx, A1) : fmaf(A1 - A0, wx, A0);
                const float bot = sxv[k] ? fmaf(B2 - B1, wx, B1) : fmaf(B1 - B0, wx, B0);
                const float xup = fmaf(bot - top, wy, top);
                rr[k] = fmaf(lam, alp - xup, xup) + gh * ahp;
            }
            *reinterpret_cast<float4*>(ydst + (size_t)H * HH + ppx * 4) =
                make_float4(rr[0], rr[1], rr[2], rr[3]);
        }
    }
}

// ---------------------------------------------------------------------------
extern "C" void kernel_launch(void* const* d_in, const int* in_sizes, int n_in,
                              void* d_out, int out_size, void* d_ws, size_t ws_size,
                              hipStream_t stream)
{
    const float* x    = (const float*)d_in[0];
    const float* w1o  = (const float*)d_in[1];
    const float* b1o  = (const float*)d_in[2];
    const float* w2o  = (const float*)d_in[3];
    const float* b2o  = (const float*)d_in[4];
    const float* w1g  = (const float*)d_in[5];
    const float* b1g  = (const float*)d_in[6];
    const float* w2g  = (const float*)d_in[7];
    const float* b2g  = (const float*)d_in[8];
    const float* beta = (const float*)d_in[9];
    float* out = (float*)d_out;
    float* wsf = (float*)d_ws;

    float* hid_o = wsf;                                  // [4][24][NP][2] pair-interleaved
    float* hid_g = hid_o + (size_t)B_N * HIDC * NP;

    // output layout: y [4,21,324,324], v [4,8,81,81], g_up [4,1,324,324]
    float* y_out = out;
    float* v_out = out + (size_t)B_N * CIN * NPH;
    float* gup   = v_out + (size_t)B_N * 8 * NP;

    k1_conv1<<<dim3((NP + 255) / 256, 8, B_N), 256, 0, stream>>>(
        x, w1o, b1o, w1g, b1g, hid_o, hid_g);
    k2up<<<dim3((NP + 31) / 32, B_N), 256, 0, stream>>>(
        x, hid_o, hid_g, w2o, b2o, w2g, b2g, beta, v_out, y_out, gup);
}

// Round 10
// 145.538 us; speedup vs baseline: 1.4649x; 1.0433x over previous
//
#include <hip/hip_runtime.h>
#include <math.h>

// Problem constants
#define B_N   4
#define CIN   21
#define HIDC  48
#define H0    81
#define NP    6561      // 81*81
#define HH    324
#define NPH   104976    // 324*324

__device__ __forceinline__ float tanh_fast(float x) {
    float e = __expf(2.f * x);
    return 1.f - 2.f / (e + 1.f);
}

// ---------------------------------------------------------------------------
// K1 v6 (round-5 proven, unchanged): conv1 both heads (21 -> 96), relu.
// ---------------------------------------------------------------------------
__global__ __launch_bounds__(256) void k1_conv1(
    const float* __restrict__ x,
    const float* __restrict__ w1o, const float* __restrict__ b1o,
    const float* __restrict__ w1g, const float* __restrict__ b1g,
    float* __restrict__ hid_o, float* __restrict__ hid_g)
{
    __shared__ __align__(16) float wt[189 * 12];  // [ict*12 + oc]
    __shared__ float bs[12];
    const int tid = threadIdx.x;
    const int grp = blockIdx.y;          // 0..7 ; 0..3 -> head_o, 4..7 -> head_g
    const int b   = blockIdx.z;
    const bool head_o = (grp < 4);
    const int ocb = (grp & 3) * 12;      // oc base within the head
    const float* wsrc = head_o ? w1o : w1g;
    for (int i = tid; i < 189 * 12; i += 256) {
        const int ict = i / 12, oc = i - ict * 12;
        wt[i] = wsrc[(ocb + oc) * 189 + ict];
    }
    if (tid < 12) bs[tid] = (head_o ? b1o : b1g)[ocb + tid];
    __syncthreads();

    const int px = blockIdx.x * 256 + tid;
    const bool valid = (px < NP);
    const int oy = px / H0, ox = px - oy * H0;
    const float* xb = x + (size_t)b * CIN * NP;

    float acc[12];
    #pragma unroll
    for (int j = 0; j < 12; j++) acc[j] = bs[j];

    for (int ic = 0; ic < CIN; ic++) {
        const float* xc = xb + ic * NP;
        float xv[9];
        #pragma unroll
        for (int ky = 0; ky < 3; ky++) {
            const int iy = oy + ky - 1;
            const bool rok = valid && ((unsigned)iy < (unsigned)H0);
            #pragma unroll
            for (int kx = 0; kx < 3; kx++) {
                const int ix = ox + kx - 1;
                const bool ok = rok && ((unsigned)ix < (unsigned)H0);
                xv[ky * 3 + kx] = ok ? xc[iy * H0 + ix] : 0.f;
            }
        }
        #pragma unroll
        for (int tap = 0; tap < 9; tap++) {
            const float4 w0 = *(const float4*)&wt[(ic * 9 + tap) * 12];
            const float4 w1 = *(const float4*)&wt[(ic * 9 + tap) * 12 + 4];
            const float4 w2 = *(const float4*)&wt[(ic * 9 + tap) * 12 + 8];
            const float wj[12] = {w0.x, w0.y, w0.z, w0.w, w1.x, w1.y, w1.z, w1.w,
                                  w2.x, w2.y, w2.z, w2.w};
            const float xvt = xv[tap];
            #pragma unroll
            for (int j = 0; j < 12; j++) acc[j] = fmaf(xvt, wj[j], acc[j]);
        }
    }

    if (valid) {
        float* outp = (head_o ? hid_o : hid_g) + ((size_t)b * HIDC + ocb) * NP + px;
        #pragma unroll
        for (int j = 0; j < 12; j++) outp[j * NP] = fmaxf(acc[j], 0.f);
    }
}

// ---------------------------------------------------------------------------
// K2UP v8: v3 (round-5 best) with the pre-conv BARRIER DELETED.
//  - Each wave stages ONLY its own 12-ic slice of wo_s/wg_s; own-wave
//    ds_write->ds_read ordering comes from the compiler's lgkmcnt, so no
//    __syncthreads is needed before the conv. Waves de-lockstep: their
//    ~900-cycle HBM stall windows decorrelate instead of convoying.
//  - xs staging is issued AFTER the conv loop (youngest vmem ops), so its
//    latency hides under conv+reduce; the existing reduce barrier's
//    vmcnt(0) drain guarantees xs visibility before the emit phase.
// Everything else (grid, conv loop, epilogue, emit) is v3 verbatim.
// ---------------------------------------------------------------------------
__global__ __launch_bounds__(256) void k2up(
    const float* __restrict__ x,
    const float* __restrict__ hid_o, const float* __restrict__ hid_g,
    const float* __restrict__ w2o, const float* __restrict__ b2o,
    const float* __restrict__ w2g, const float* __restrict__ b2g,
    const float* __restrict__ beta,
    float* __restrict__ v_out, float* __restrict__ y_out,
    float* __restrict__ gup_out)
{
    __shared__ __align__(16) float wo_s[HIDC * 9 * 8];  // 13824 B
    __shared__ float wg_s[HIDC * 9];                    // 1728 B
    __shared__ float red[4][32][12];                    // 6144 B
    __shared__ float res_s[32][29];                     // 3712 B, stride 29 coprime w/ 32
    __shared__ float xs[CIN][4][H0];                    // 27216 B: 4 reflected rows
    const int tid = threadIdx.x;
    const int b = blockIdx.y;

    const int pl  = tid & 31;
    const int s   = tid >> 5;                // 0..7
    const int w   = tid >> 6;                // wave
    const int px0 = blockIdx.x * 32;
    const int px  = px0 + pl;
    const bool valid = (px < NP);
    const int py  = px / H0, pxc = px - py * H0;
    const int pr0 = px0 / H0;                // first row touched by this block

    // ---- per-wave weight staging (NO barrier) ---------------------------
    // wave w covers s=2w,2w+1 -> ic 12w..12w+11 -> wo_s rows [12w*9, 12w*9+108)
    {
        const int lane = tid & 63;
        const int r0 = w * 12 * 9;           // 108 rows per wave
        for (int i = lane; i < 108 * 8; i += 64) {
            const int rr = i >> 3, d = i & 7;
            wo_s[(r0 + rr) * 8 + d] = w2o[d * (HIDC * 9) + r0 + rr];
        }
        for (int i = lane; i < 108; i += 64)
            wg_s[r0 + i] = w2g[r0 + i];
    }
    // own-wave lgkmcnt orders these ds_writes before the conv's ds_reads.

    // ---- conv2 partials (v3 verbatim) -----------------------------------
    const int ic0 = s * 6;
    const float* po = hid_o + ((size_t)b * HIDC + ic0) * NP;
    const float* pg = hid_g + ((size_t)b * HIDC + ic0) * NP;

    float a[8] = {0.f, 0.f, 0.f, 0.f, 0.f, 0.f, 0.f, 0.f};
    float ag = 0.f;

    #pragma unroll 1
    for (int ky = 0; ky < 3; ky++) {
        const int iy = py + ky - 1;
        const bool rok = valid && ((unsigned)iy < (unsigned)H0);
        #pragma unroll
        for (int kx = 0; kx < 3; kx++) {
            const int ix = pxc + kx - 1;
            const bool ok = rok && ((unsigned)ix < (unsigned)H0);
            const int off = iy * H0 + ix;
            const int tap = ky * 3 + kx;
            #pragma unroll
            for (int j = 0; j < 6; j++) {
                const float vo = ok ? po[j * NP + off] : 0.f;
                const float vg = ok ? pg[j * NP + off] : 0.f;
                const int wb = ((ic0 + j) * 9 + tap) * 8;
                const float4 wA = *(const float4*)&wo_s[wb];
                const float4 wB = *(const float4*)&wo_s[wb + 4];
                a[0] = fmaf(vo, wA.x, a[0]); a[1] = fmaf(vo, wA.y, a[1]);
                a[2] = fmaf(vo, wA.z, a[2]); a[3] = fmaf(vo, wA.w, a[3]);
                a[4] = fmaf(vo, wB.x, a[4]); a[5] = fmaf(vo, wB.y, a[5]);
                a[6] = fmaf(vo, wB.z, a[6]); a[7] = fmaf(vo, wB.w, a[7]);
                ag = fmaf(vg, wg_s[(ic0 + j) * 9 + tap], ag);
            }
        }
    }

    // ---- xs staging: issued AFTER conv (youngest vmem; drains at the
    //      reduce barrier below, hidden under conv/reduce/epilogue) --------
    {
        const float* xb = x + (size_t)b * CIN * NP;
        for (int i = tid; i < CIN * 4 * H0; i += 256) {
            const int c = i / (4 * H0), rem = i - c * (4 * H0);
            const int t = rem / H0, col = rem - t * H0;
            int r = pr0 - 1 + t;
            r = (r < 0) ? -r : r;
            r = (r > H0 - 1) ? 2 * (H0 - 1) - r : r;
            (&xs[0][0][0])[i] = xb[c * NP + r * H0 + col];
        }
    }

    #pragma unroll
    for (int n = 0; n < 8; n++) a[n] += __shfl_xor(a[n], 32);
    ag += __shfl_xor(ag, 32);
    if ((tid & 32) == 0) {
        #pragma unroll
        for (int n = 0; n < 8; n++) red[w][pl][n] = a[n];
        red[w][pl][8] = ag;
    }
    __syncthreads();

    // ---- mask epilogue (32 threads) -------------------------------------
    if (tid < 32 && valid) {
        float v[8];
        #pragma unroll
        for (int n = 0; n < 8; n++)
            v[n] = tanh_fast(red[0][tid][n] + red[1][tid][n] + red[2][tid][n]
                             + red[3][tid][n] + b2o[n]);
        const float agf = red[0][tid][8] + red[1][tid][8] + red[2][tid][8]
                        + red[3][tid][8] + b2g[0];
        const float g = 1.f / (1.f + __expf(-agf));

        constexpr float DT[8][9] = {
            {-1, 0, 1, -1, 0, 1, -1, 0, 1},
            {-1,-1, 0, -1, 0, 1,  0, 1, 1},
            {-1,-1,-1,  0, 0, 0,  1, 1, 1},
            { 0,-1,-1,  1, 0,-1,  1, 1, 0},
            { 1, 0,-1,  1, 0,-1,  1, 0,-1},
            { 1, 1, 0,  1, 0,-1,  0,-1,-1},
            { 1, 1, 1,  0, 0, 0, -1,-1,-1},
            { 0, 1, 1, -1, 0, 1, -1,-1, 0}};
        float ker[9];
        #pragma unroll
        for (int n = 0; n < 9; n++) {
            float t = 0.f;
            #pragma unroll
            for (int d = 0; d < 8; d++) t += v[d] * DT[d][n];
            ker[n] = -0.125f * t;
        }
        ker[4] += 2.5f;
        float mx = ker[0];
        #pragma unroll
        for (int n = 1; n < 9; n++) mx = fmaxf(mx, ker[n]);
        float exn[9], sum = 0.f;
        #pragma unroll
        for (int n = 0; n < 9; n++) { exn[n] = __expf((ker[n] - mx) * 2.0f); sum += exn[n]; }
        const float rs = 1.f / sum;
        float mean = 0.f;
        #pragma unroll
        for (int n = 0; n < 9; n++) mean += ker[n];
        mean *= (1.f / 9.f);
        float den = 1e-8f;
        #pragma unroll
        for (int n = 0; n < 9; n++) den += fabsf(ker[n] - mean);
        const float rd = 1.f / den;

        #pragma unroll
        for (int n = 0; n < 8; n++) res_s[tid][n] = v[n];
        res_s[tid][8] = g;
        #pragma unroll
        for (int n = 0; n < 9; n++) {
            res_s[tid][9 + n]  = exn[n] * rs;
            res_s[tid][18 + n] = (ker[n] - mean) * rd;
        }
    }
    __syncthreads();

    // ---- v scatter (one iteration: 8 planes x 32 px) --------------------
    if (valid) v_out[((size_t)b * 8 + s) * NP + px] = res_s[pl][s];

    // ---- emit: 22 planes x 32 px items, all data from LDS ---------------
    const float tb = tanh_fast(beta[0]);
    for (int i = tid; i < 22 * 32; i += 256) {
        const int plane = i >> 5, pp = i & 31;
        const int p = px0 + pp;
        if (p >= NP) continue;
        const int ppy = p / H0, ppx = p - ppy * H0;
        const float gv = res_s[pp][8];

        if (plane == 21) {
            float* gdst = gup_out + (size_t)b * NPH;
            #pragma unroll
            for (int dh = 0; dh < 4; dh++)
                *reinterpret_cast<float4*>(gdst + (size_t)(ppy * 4 + dh) * HH + ppx * 4) =
                    make_float4(gv, gv, gv, gv);
            continue;
        }

        // 3x3 reflected window from LDS row cache
        const int d0 = ppy - pr0;        // 0 or 1
        const int xm = (ppx == 0) ? 1 : ppx - 1;
        const int xp = (ppx == H0 - 1) ? H0 - 2 : ppx + 1;
        float w9[9];
        #pragma unroll
        for (int t = 0; t < 3; t++) {
            w9[t * 3 + 0] = xs[plane][d0 + t][xm];
            w9[t * 3 + 1] = xs[plane][d0 + t][ppx];
            w9[t * 3 + 2] = xs[plane][d0 + t][xp];
        }

        float alp = 0.f, ahp = 0.f;
        #pragma unroll
        for (int t = 0; t < 9; t++) {
            alp = fmaf(w9[t], res_s[pp][9 + t],  alp);
            ahp = fmaf(w9[t], res_s[pp][18 + t], ahp);
        }

        const float lam = 0.15f * (1.f - gv);
        const float gh  = tb * gv;

        // per-pixel bilinear coefficients
        int sxv[4]; float wxv[4];
        #pragma unroll
        for (int k = 0; k < 4; k++) {
            const int W = ppx * 4 + k;
            const float xsf = (float)W * (80.f / 323.f);
            int x0 = (int)xsf;
            if (x0 > H0 - 2) x0 = H0 - 2;
            wxv[k] = xsf - (float)x0;
            sxv[k] = x0 - ppx + 1;       // 0 or 1
        }

        float* ydst = y_out + ((size_t)b * CIN + plane) * NPH;
        #pragma unroll
        for (int dh = 0; dh < 4; dh++) {
            const int H = ppy * 4 + dh;
            const float ysf = (float)H * (80.f / 323.f);
            int y0 = (int)ysf;
            if (y0 > H0 - 2) y0 = H0 - 2;
            const float wy = ysf - (float)y0;
            const int sy = y0 - ppy + 1;  // 0 or 1
            const float A0 = sy ? w9[3] : w9[0];
            const float A1 = sy ? w9[4] : w9[1];
            const float A2 = sy ? w9[5] : w9[2];
            const float B0 = sy ? w9[6] : w9[3];
            const float B1 = sy ? w9[7] : w9[4];
            const float B2 = sy ? w9[8] : w9[5];
            float rr[4];
            #pragma unroll
            for (int k = 0; k < 4; k++) {
                const float wx = wxv[k];
                const float top = sxv[k] ? fmaf(A2 - A1, wx, A1) : fmaf(A1 - A0, wx, A0);
                const float bot = sxv[k] ? fmaf(B2 - B1, wx, B1) : fmaf(B1 - B0, wx, B0);
                const float xup = fmaf(bot - top, wy, top);
                rr[k] = fmaf(lam, alp - xup, xup) + gh * ahp;
            }
            *reinterpret_cast<float4*>(ydst + (size_t)H * HH + ppx * 4) =
                make_float4(rr[0], rr[1], rr[2], rr[3]);
        }
    }
}

// ---------------------------------------------------------------------------
extern "C" void kernel_launch(void* const* d_in, const int* in_sizes, int n_in,
                              void* d_out, int out_size, void* d_ws, size_t ws_size,
                              hipStream_t stream)
{
    const float* x    = (const float*)d_in[0];
    const float* w1o  = (const float*)d_in[1];
    const float* b1o  = (const float*)d_in[2];
    const float* w2o  = (const float*)d_in[3];
    const float* b2o  = (const float*)d_in[4];
    const float* w1g  = (const float*)d_in[5];
    const float* b1g  = (const float*)d_in[6];
    const float* w2g  = (const float*)d_in[7];
    const float* b2g  = (const float*)d_in[8];
    const float* beta = (const float*)d_in[9];
    float* out = (float*)d_out;
    float* wsf = (float*)d_ws;

    float* hid_o = wsf;
    float* hid_g = hid_o + (size_t)B_N * HIDC * NP;

    // output layout: y [4,21,324,324], v [4,8,81,81], g_up [4,1,324,324]
    float* y_out = out;
    float* v_out = out + (size_t)B_N * CIN * NPH;
    float* gup   = v_out + (size_t)B_N * 8 * NP;

    k1_conv1<<<dim3((NP + 255) / 256, 8, B_N), 256, 0, stream>>>(
        x, w1o, b1o, w1g, b1g, hid_o, hid_g);
    k2up<<<dim3((NP + 31) / 32, B_N), 256, 0, stream>>>(
        x, hid_o, hid_g, w2o, b2o, w2g, b2g, beta, v_out, y_out, gup);
}

// Round 11
// 144.792 us; speedup vs baseline: 1.4725x; 1.0052x over previous
//
#include <hip/hip_runtime.h>
#include <math.h>

// Problem constants
#define B_N   4
#define CIN   21
#define HIDC  48
#define H0    81
#define NP    6561      // 81*81
#define HH    324
#define NPH   104976    // 324*324

__device__ __forceinline__ float tanh_fast(float x) {
    float e = __expf(2.f * x);
    return 1.f - 2.f / (e + 1.f);
}

// ---------------------------------------------------------------------------
// K1 v6: conv1 both heads (21 -> 96 = 48 o + 48 g), relu. MLP-first layout:
// block = 256 consecutive pixels, blockIdx.y = 12-oc group (8 groups of 12).
// ---------------------------------------------------------------------------
__global__ __launch_bounds__(256) void k1_conv1(
    const float* __restrict__ x,
    const float* __restrict__ w1o, const float* __restrict__ b1o,
    const float* __restrict__ w1g, const float* __restrict__ b1g,
    float* __restrict__ hid_o, float* __restrict__ hid_g)
{
    __shared__ __align__(16) float wt[189 * 12];  // [ict*12 + oc]
    __shared__ float bs[12];
    const int tid = threadIdx.x;
    const int grp = blockIdx.y;          // 0..7 ; 0..3 -> head_o, 4..7 -> head_g
    const int b   = blockIdx.z;
    const bool head_o = (grp < 4);
    const int ocb = (grp & 3) * 12;      // oc base within the head
    const float* wsrc = head_o ? w1o : w1g;
    for (int i = tid; i < 189 * 12; i += 256) {
        const int ict = i / 12, oc = i - ict * 12;
        wt[i] = wsrc[(ocb + oc) * 189 + ict];
    }
    if (tid < 12) bs[tid] = (head_o ? b1o : b1g)[ocb + tid];
    __syncthreads();

    const int px = blockIdx.x * 256 + tid;
    const bool valid = (px < NP);
    const int oy = px / H0, ox = px - oy * H0;
    const float* xb = x + (size_t)b * CIN * NP;

    float acc[12];
    #pragma unroll
    for (int j = 0; j < 12; j++) acc[j] = bs[j];

    for (int ic = 0; ic < CIN; ic++) {
        const float* xc = xb + ic * NP;
        float xv[9];
        #pragma unroll
        for (int ky = 0; ky < 3; ky++) {
            const int iy = oy + ky - 1;
            const bool rok = valid && ((unsigned)iy < (unsigned)H0);
            #pragma unroll
            for (int kx = 0; kx < 3; kx++) {
                const int ix = ox + kx - 1;
                const bool ok = rok && ((unsigned)ix < (unsigned)H0);
                xv[ky * 3 + kx] = ok ? xc[iy * H0 + ix] : 0.f;
            }
        }
        #pragma unroll
        for (int tap = 0; tap < 9; tap++) {
            const float4 w0 = *(const float4*)&wt[(ic * 9 + tap) * 12];
            const float4 w1 = *(const float4*)&wt[(ic * 9 + tap) * 12 + 4];
            const float4 w2 = *(const float4*)&wt[(ic * 9 + tap) * 12 + 8];
            const float wj[12] = {w0.x, w0.y, w0.z, w0.w, w1.x, w1.y, w1.z, w1.w,
                                  w2.x, w2.y, w2.z, w2.w};
            const float xvt = xv[tap];
            #pragma unroll
            for (int j = 0; j < 12; j++) acc[j] = fmaf(xvt, wj[j], acc[j]);
        }
    }

    if (valid) {
        float* outp = (head_o ? hid_o : hid_g) + ((size_t)b * HIDC + ocb) * NP + px;
        #pragma unroll
        for (int j = 0; j < 12; j++) outp[j * NP] = fmaxf(acc[j], 0.f);
    }
}

// ---------------------------------------------------------------------------
// K2UP v3 (round-5 best, final): conv2+masks+upsample. x staged in LDS
// (4 reflected rows x 21 ch, coalesced, drained by the weights barrier);
// emit phase is pure LDS+VALU. Session evidence (rounds 4-10): conv2 is
// latency-bound at ~44 us regardless of load shaping (register prefetch
// spills; LDS-hid adds traffic; full unroll spills; padded borders neutral;
// float2 pairs neutral; barrier removal neutral) -- this configuration is
// the empirical optimum of the family.
// ---------------------------------------------------------------------------
__global__ __launch_bounds__(256) void k2up(
    const float* __restrict__ x,
    const float* __restrict__ hid_o, const float* __restrict__ hid_g,
    const float* __restrict__ w2o, const float* __restrict__ b2o,
    const float* __restrict__ w2g, const float* __restrict__ b2g,
    const float* __restrict__ beta,
    float* __restrict__ v_out, float* __restrict__ y_out,
    float* __restrict__ gup_out)
{
    __shared__ __align__(16) float wo_s[HIDC * 9 * 8];  // 13824 B
    __shared__ float wg_s[HIDC * 9];                    // 1728 B
    __shared__ float red[4][32][12];                    // 6144 B
    __shared__ float res_s[32][29];                     // 3712 B, stride 29 coprime w/ 32
    __shared__ float xs[CIN][4][H0];                    // 27216 B: 4 reflected rows
    const int tid = threadIdx.x;
    const int b = blockIdx.y;

    const int pl  = tid & 31;
    const int s   = tid >> 5;                // 0..7
    const int w   = tid >> 6;                // wave
    const int px0 = blockIdx.x * 32;
    const int px  = px0 + pl;
    const bool valid = (px < NP);
    const int py  = px / H0, pxc = px - py * H0;
    const int pr0 = px0 / H0;                // first row touched by this block

    // ---- stage x rows: slot t = reflect(pr0-1+t), fully coalesced -------
    {
        const float* xb = x + (size_t)b * CIN * NP;
        for (int i = tid; i < CIN * 4 * H0; i += 256) {
            const int c = i / (4 * H0), rem = i - c * (4 * H0);
            const int t = rem / H0, col = rem - t * H0;
            int r = pr0 - 1 + t;
            r = (r < 0) ? -r : r;
            r = (r > H0 - 1) ? 2 * (H0 - 1) - r : r;
            (&xs[0][0][0])[i] = xb[c * NP + r * H0 + col];
        }
    }

    // ---- stage conv2 weights --------------------------------------------
    for (int i = tid; i < HIDC * 9 * 8; i += 256) {
        const int d = i / (HIDC * 9), r = i - d * (HIDC * 9);
        wo_s[r * 8 + d] = w2o[i];
    }
    for (int i = tid; i < HIDC * 9; i += 256) wg_s[i] = w2g[i];
    __syncthreads();

    // ---- conv2 partials -------------------------------------------------
    const int ic0 = s * 6;
    const float* po = hid_o + ((size_t)b * HIDC + ic0) * NP;
    const float* pg = hid_g + ((size_t)b * HIDC + ic0) * NP;

    float a[8] = {0.f, 0.f, 0.f, 0.f, 0.f, 0.f, 0.f, 0.f};
    float ag = 0.f;

    #pragma unroll 1
    for (int ky = 0; ky < 3; ky++) {
        const int iy = py + ky - 1;
        const bool rok = valid && ((unsigned)iy < (unsigned)H0);
        #pragma unroll
        for (int kx = 0; kx < 3; kx++) {
            const int ix = pxc + kx - 1;
            const bool ok = rok && ((unsigned)ix < (unsigned)H0);
            const int off = iy * H0 + ix;
            const int tap = ky * 3 + kx;
            #pragma unroll
            for (int j = 0; j < 6; j++) {
                const float vo = ok ? po[j * NP + off] : 0.f;
                const float vg = ok ? pg[j * NP + off] : 0.f;
                const int wb = ((ic0 + j) * 9 + tap) * 8;
                const float4 wA = *(const float4*)&wo_s[wb];
                const float4 wB = *(const float4*)&wo_s[wb + 4];
                a[0] = fmaf(vo, wA.x, a[0]); a[1] = fmaf(vo, wA.y, a[1]);
                a[2] = fmaf(vo, wA.z, a[2]); a[3] = fmaf(vo, wA.w, a[3]);
                a[4] = fmaf(vo, wB.x, a[4]); a[5] = fmaf(vo, wB.y, a[5]);
                a[6] = fmaf(vo, wB.z, a[6]); a[7] = fmaf(vo, wB.w, a[7]);
                ag = fmaf(vg, wg_s[(ic0 + j) * 9 + tap], ag);
            }
        }
    }

    #pragma unroll
    for (int n = 0; n < 8; n++) a[n] += __shfl_xor(a[n], 32);
    ag += __shfl_xor(ag, 32);
    if ((tid & 32) == 0) {
        #pragma unroll
        for (int n = 0; n < 8; n++) red[w][pl][n] = a[n];
        red[w][pl][8] = ag;
    }
    __syncthreads();

    // ---- mask epilogue (32 threads) -------------------------------------
    if (tid < 32 && valid) {
        float v[8];
        #pragma unroll
        for (int n = 0; n < 8; n++)
            v[n] = tanh_fast(red[0][tid][n] + red[1][tid][n] + red[2][tid][n]
                             + red[3][tid][n] + b2o[n]);
        const float agf = red[0][tid][8] + red[1][tid][8] + red[2][tid][8]
                        + red[3][tid][8] + b2g[0];
        const float g = 1.f / (1.f + __expf(-agf));

        constexpr float DT[8][9] = {
            {-1, 0, 1, -1, 0, 1, -1, 0, 1},
            {-1,-1, 0, -1, 0, 1,  0, 1, 1},
            {-1,-1,-1,  0, 0, 0,  1, 1, 1},
            { 0,-1,-1,  1, 0,-1,  1, 1, 0},
            { 1, 0,-1,  1, 0,-1,  1, 0,-1},
            { 1, 1, 0,  1, 0,-1,  0,-1,-1},
            { 1, 1, 1,  0, 0, 0, -1,-1,-1},
            { 0, 1, 1, -1, 0, 1, -1,-1, 0}};
        float ker[9];
        #pragma unroll
        for (int n = 0; n < 9; n++) {
            float t = 0.f;
            #pragma unroll
            for (int d = 0; d < 8; d++) t += v[d] * DT[d][n];
            ker[n] = -0.125f * t;
        }
        ker[4] += 2.5f;
        float mx = ker[0];
        #pragma unroll
        for (int n = 1; n < 9; n++) mx = fmaxf(mx, ker[n]);
        float exn[9], sum = 0.f;
        #pragma unroll
        for (int n = 0; n < 9; n++) { exn[n] = __expf((ker[n] - mx) * 2.0f); sum += exn[n]; }
        const float rs = 1.f / sum;
        float mean = 0.f;
        #pragma unroll
        for (int n = 0; n < 9; n++) mean += ker[n];
        mean *= (1.f / 9.f);
        float den = 1e-8f;
        #pragma unroll
        for (int n = 0; n < 9; n++) den += fabsf(ker[n] - mean);
        const float rd = 1.f / den;

        #pragma unroll
        for (int n = 0; n < 8; n++) res_s[tid][n] = v[n];
        res_s[tid][8] = g;
        #pragma unroll
        for (int n = 0; n < 9; n++) {
            res_s[tid][9 + n]  = exn[n] * rs;
            res_s[tid][18 + n] = (ker[n] - mean) * rd;
        }
    }
    __syncthreads();

    // ---- v scatter (one iteration: 8 planes x 32 px) --------------------
    if (valid) v_out[((size_t)b * 8 + s) * NP + px] = res_s[pl][s];

    // ---- emit: 22 planes x 32 px items, all data from LDS ---------------
    const float tb = tanh_fast(beta[0]);
    for (int i = tid; i < 22 * 32; i += 256) {
        const int plane = i >> 5, pp = i & 31;
        const int p = px0 + pp;
        if (p >= NP) continue;
        const int ppy = p / H0, ppx = p - ppy * H0;
        const float gv = res_s[pp][8];

        if (plane == 21) {
            float* gdst = gup_out + (size_t)b * NPH;
            #pragma unroll
            for (int dh = 0; dh < 4; dh++)
                *reinterpret_cast<float4*>(gdst + (size_t)(ppy * 4 + dh) * HH + ppx * 4) =
                    make_float4(gv, gv, gv, gv);
            continue;
        }

        // 3x3 reflected window from LDS row cache
        const int d0 = ppy - pr0;        // 0 or 1
        const int xm = (ppx == 0) ? 1 : ppx - 1;
        const int xp = (ppx == H0 - 1) ? H0 - 2 : ppx + 1;
        float w9[9];
        #pragma unroll
        for (int t = 0; t < 3; t++) {
            w9[t * 3 + 0] = xs[plane][d0 + t][xm];
            w9[t * 3 + 1] = xs[plane][d0 + t][ppx];
            w9[t * 3 + 2] = xs[plane][d0 + t][xp];
        }

        float alp = 0.f, ahp = 0.f;
        #pragma unroll
        for (int t = 0; t < 9; t++) {
            alp = fmaf(w9[t], res_s[pp][9 + t],  alp);
            ahp = fmaf(w9[t], res_s[pp][18 + t], ahp);
        }

        const float lam = 0.15f * (1.f - gv);
        const float gh  = tb * gv;

        // per-pixel bilinear coefficients
        int sxv[4]; float wxv[4];
        #pragma unroll
        for (int k = 0; k < 4; k++) {
            const int W = ppx * 4 + k;
            const float xsf = (float)W * (80.f / 323.f);
            int x0 = (int)xsf;
            if (x0 > H0 - 2) x0 = H0 - 2;
            wxv[k] = xsf - (float)x0;
            sxv[k] = x0 - ppx + 1;       // 0 or 1
        }

        float* ydst = y_out + ((size_t)b * CIN + plane) * NPH;
        #pragma unroll
        for (int dh = 0; dh < 4; dh++) {
            const int H = ppy * 4 + dh;
            const float ysf = (float)H * (80.f / 323.f);
            int y0 = (int)ysf;
            if (y0 > H0 - 2) y0 = H0 - 2;
            const float wy = ysf - (float)y0;
            const int sy = y0 - ppy + 1;  // 0 or 1
            const float A0 = sy ? w9[3] : w9[0];
            const float A1 = sy ? w9[4] : w9[1];
            const float A2 = sy ? w9[5] : w9[2];
            const float B0 = sy ? w9[6] : w9[3];
            const float B1 = sy ? w9[7] : w9[4];
            const float B2 = sy ? w9[8] : w9[5];
            float rr[4];
            #pragma unroll
            for (int k = 0; k < 4; k++) {
                const float wx = wxv[k];
                const float top = sxv[k] ? fmaf(A2 - A1, wx, A1) : fmaf(A1 - A0, wx, A0);
                const float bot = sxv[k] ? fmaf(B2 - B1, wx, B1) : fmaf(B1 - B0, wx, B0);
                const float xup = fmaf(bot - top, wy, top);
                rr[k] = fmaf(lam, alp - xup, xup) + gh * ahp;
            }
            *reinterpret_cast<float4*>(ydst + (size_t)H * HH + ppx * 4) =
                make_float4(rr[0], rr[1], rr[2], rr[3]);
        }
    }
}

// ---------------------------------------------------------------------------
extern "C" void kernel_launch(void* const* d_in, const int* in_sizes, int n_in,
                              void* d_out, int out_size, void* d_ws, size_t ws_size,
                              hipStream_t stream)
{
    const float* x    = (const float*)d_in[0];
    const float* w1o  = (const float*)d_in[1];
    const float* b1o  = (const float*)d_in[2];
    const float* w2o  = (const float*)d_in[3];
    const float* b2o  = (const float*)d_in[4];
    const float* w1g  = (const float*)d_in[5];
    const float* b1g  = (const float*)d_in[6];
    const float* w2g  = (const float*)d_in[7];
    const float* b2g  = (const float*)d_in[8];
    const float* beta = (const float*)d_in[9];
    float* out = (float*)d_out;
    float* wsf = (float*)d_ws;

    float* hid_o = wsf;
    float* hid_g = hid_o + (size_t)B_N * HIDC * NP;

    // output layout: y [4,21,324,324], v [4,8,81,81], g_up [4,1,324,324]
    float* y_out = out;
    float* v_out = out + (size_t)B_N * CIN * NPH;
    float* gup   = v_out + (size_t)B_N * 8 * NP;

    k1_conv1<<<dim3((NP + 255) / 256, 8, B_N), 256, 0, stream>>>(
        x, w1o, b1o, w1g, b1g, hid_o, hid_g);
    k2up<<<dim3((NP + 31) / 32, B_N), 256, 0, stream>>>(
        x, hid_o, hid_g, w2o, b2o, w2g, b2g, beta, v_out, y_out, gup);
}